// Round 1
// baseline (867.453 us; speedup 1.0000x reference)
//
#include <hip/hip_runtime.h>

// GradewiseLayerNorm: x (2048, 4096, 16) f32, scale (5,) f32.
// Per row of 16: 5 grade slices [0,1),[1,5),[5,11),[11,15),[15,16).
// out[..., a:b] = x[..., a:b] / sqrt(sum(x[a:b]^2) + 1e-6) * scale[g]
// Memory-bound: 1 GiB total traffic -> ~170us floor at 6.3 TB/s.

constexpr float EPS = 1e-6f;

__global__ __launch_bounds__(256) void gln_kernel(
    const float4* __restrict__ x4,
    const float* __restrict__ scale,
    float4* __restrict__ out4,
    int n_rows)
{
    int row = blockIdx.x * blockDim.x + threadIdx.x;
    if (row >= n_rows) return;

    const float4* xp = x4 + (size_t)row * 4;
    float4 v0 = xp[0];
    float4 v1 = xp[1];
    float4 v2 = xp[2];
    float4 v3 = xp[3];

    // Group sums of squares (boundaries at elements 1, 5, 11, 15).
    float g0 = v0.x * v0.x;
    float g1 = v0.y * v0.y + v0.z * v0.z + v0.w * v0.w + v1.x * v1.x;
    float g2 = v1.y * v1.y + v1.z * v1.z + v1.w * v1.w
             + v2.x * v2.x + v2.y * v2.y + v2.z * v2.z;
    float g3 = v2.w * v2.w + v3.x * v3.x + v3.y * v3.y + v3.z * v3.z;
    float g4 = v3.w * v3.w;

    // scale[g] / sqrt(g + eps); sum-of-squares >= 0 so abs() is a no-op.
    float r0 = scale[0] * rsqrtf(g0 + EPS);
    float r1 = scale[1] * rsqrtf(g1 + EPS);
    float r2 = scale[2] * rsqrtf(g2 + EPS);
    float r3 = scale[3] * rsqrtf(g3 + EPS);
    float r4 = scale[4] * rsqrtf(g4 + EPS);

    float4 o0, o1, o2, o3;
    o0.x = v0.x * r0;
    o0.y = v0.y * r1;  o0.z = v0.z * r1;  o0.w = v0.w * r1;
    o1.x = v1.x * r1;
    o1.y = v1.y * r2;  o1.z = v1.z * r2;  o1.w = v1.w * r2;
    o2.x = v2.x * r2;  o2.y = v2.y * r2;  o2.z = v2.z * r2;
    o2.w = v2.w * r3;
    o3.x = v3.x * r3;  o3.y = v3.y * r3;  o3.z = v3.z * r3;
    o3.w = v3.w * r4;

    float4* op = out4 + (size_t)row * 4;
    op[0] = o0;
    op[1] = o1;
    op[2] = o2;
    op[3] = o3;
}

extern "C" void kernel_launch(void* const* d_in, const int* in_sizes, int n_in,
                              void* d_out, int out_size, void* d_ws, size_t ws_size,
                              hipStream_t stream) {
    const float* x = (const float*)d_in[0];
    const float* scale = (const float*)d_in[1];
    float* out = (float*)d_out;

    int n_rows = in_sizes[0] / 16;  // 2048*4096 = 8,388,608
    const int block = 256;
    int grid = (n_rows + block - 1) / block;

    gln_kernel<<<grid, block, 0, stream>>>(
        (const float4*)x, scale, (float4*)out, n_rows);
}